// Round 1
// 615.786 us; speedup vs baseline: 1.0425x; 1.0425x over previous
//
#include <hip/hip_runtime.h>
#include <cstddef>

#define AZ -999999.0f

typedef float  f32x4  __attribute__((ext_vector_type(4)));
typedef short  s16x8  __attribute__((ext_vector_type(8)));
typedef __bf16 bf16x8 __attribute__((ext_vector_type(8)));
typedef unsigned short ushort_t;

// HW RNE f32->bf16 (compiler emits v_cvt_pk_bf16_f32 on gfx950)
__device__ __forceinline__ ushort_t f2bf(float f) {
    return __builtin_bit_cast(ushort_t, (__bf16)f);
}

__device__ __forceinline__ f32x4 mfma16(s16x8 a, s16x8 b, f32x4 c) {
    return __builtin_amdgcn_mfma_f32_16x16x32_bf16(
        __builtin_bit_cast(bf16x8, a), __builtin_bit_cast(bf16x8, b), c, 0, 0, 0);
}

// async global->LDS, 16B per lane; LDS dest = wave-uniform base + lane*16
__device__ __forceinline__ void gl2lds16(const void* g, void* l) {
    __builtin_amdgcn_global_load_lds(
        (const __attribute__((address_space(1))) unsigned int*)g,
        (__attribute__((address_space(3))) unsigned int*)l, 16, 0, 0);
}

// ---- combined setup: weight transposes+casts, Wu swizzle, edge meta ----
// blocks [0,768): W1T   [768,1024): W2T   [1024,1536): WeT
// [1536,1552): WuTs (pre-swizzled)   [1552,1943): meta
__global__ void setup_kernel(
    const float* __restrict__ W1, const float* __restrict__ W2,
    const float* __restrict__ We, const float* __restrict__ Wu,
    ushort_t* __restrict__ W1T, ushort_t* __restrict__ W2T,
    ushort_t* __restrict__ WeT, ushort_t* __restrict__ WuTs,
    const int* __restrict__ pidx, const int* __restrict__ cidx,
    const int* __restrict__ tl, const int* __restrict__ obs,
    int* __restrict__ meta, int E)
{
    int b = blockIdx.x, t = threadIdx.x;
    if (b < 768) {
        int idx = b * 256 + t; int k = idx >> 8, n = idx & 255;
        W1T[(size_t)n * 768 + k] = f2bf(W1[idx]);
    } else if (b < 1024) {
        int idx = (b - 768) * 256 + t; int k = idx >> 8, n = idx & 255;
        W2T[n * 256 + k] = f2bf(W2[idx]);
    } else if (b < 1536) {
        int idx = (b - 1024) * 256 + t; int k = idx >> 8, n = idx & 255;
        WeT[(size_t)n * 512 + k] = f2bf(We[idx]);
    } else if (b < 1552) {
        int idx = (b - 1536) * 256 + t; int k = idx >> 4, c = idx & 15;
        // WuT[c][k], stored with chunk swizzle: chunk' = (k>>3) ^ (c&7)
        WuTs[c * 256 + (((k >> 3) ^ (c & 7)) << 3) + (k & 7)] = f2bf(Wu[idx]);
    } else {
        int e = (b - 1552) * 256 + t;
        if (e < E) {
            int p = pidx[e], c = cidx[e];
            meta[e] = (tl[p] & 15) | ((tl[c] & 15) << 4)
                    | ((obs[p] & 1) << 8) | ((obs[c] & 1) << 9);
        }
    }
}

// ---- main GEMM: 64 rows x 256 cols per block (A read exactly once) -----
// per-wave inner loop identical to the verified m97 structure (64x64,
// acc[4][4]); only staging geometry differs. AMODE 0: f32 A (features),
// AMODE 2: bf16 A gathered via parent/child node ids.
template<int AMODE, int EPI>
__global__ __launch_bounds__(256) void gemm_kernel(
    const void* __restrict__ Aptr, const ushort_t* __restrict__ BT,
    const float* __restrict__ bias, void* __restrict__ outp,
    int M, int K,
    const int* __restrict__ parent_idx, const int* __restrict__ child_idx,
    const int* __restrict__ meta)
{
    constexpr int ABYTES = (AMODE == 0) ? 8192 : 4096;   // 64x32 f32 or bf16
    __shared__ __align__(16) char smem[ABYTES + 16384];
    float*    Asf = (float*)smem;
    ushort_t* Ash = (ushort_t*)smem;
    ushort_t* Bsh = (ushort_t*)(smem + ABYTES);          // 256 x 32 bf16

    const int tid  = threadIdx.x;
    const int lane = tid & 63, wave = tid >> 6;
    const int row0 = blockIdx.y * 64;
    const int wc   = wave * 64;
    const int quad = lane >> 4, l16 = lane & 15;
    const int c4   = lane & 3;

    // ---- B staging: 4 rounds of 64 rows; row = j*64 + (tid>>2) ----
    const int rB  = tid >> 2;                  // 0..63
    const int gcB = c4 ^ ((rB >> 1) & 3);      // 16B-chunk XOR swizzle
    size_t   b_off[4]; unsigned lds_b[4];
#pragma unroll
    for (int j = 0; j < 4; ++j) {
        b_off[j] = (size_t)(j * 64 + rB) * K + gcB * 8;
        lds_b[j] = (unsigned)(j * 64 + wave * 16) * 64;
    }

    // ---- A staging ----
    size_t a_off[2]; unsigned lds_a[2];
    int pn = 0, cn = 0; unsigned lds_a0 = 0, a_col = 0;
    if constexpr (AMODE == 0) {
        // 2 rounds of 32 rows (f32); row = j*32 + (tid>>3)
        const int c8 = tid & 7, r8 = tid >> 3;   // r8: 0..31
        const int gcA = c8 ^ (r8 & 7);
#pragma unroll
        for (int j = 0; j < 2; ++j) {
            int gr = row0 + j * 32 + r8; if (gr > M - 1) gr = M - 1;
            a_off[j] = (size_t)gr * K + gcA * 4;
            lds_a[j] = (unsigned)(j * 32 + wave * 8) * 128;
        }
    } else {
        // 1 round of 64 rows (bf16 gather); row = tid>>2
        const int rA = tid >> 2;                 // 0..63
        const int gcA2 = c4 ^ ((rA >> 1) & 3);
        int gr = row0 + rA; if (gr > M - 1) gr = M - 1;
        pn = parent_idx[gr]; cn = child_idx[gr];
        a_col  = gcA2 * 8;
        lds_a0 = (unsigned)(wave * 16) * 64;
    }

    const f32x4 fz = {0.f, 0.f, 0.f, 0.f};
    f32x4 acc[4][4];
#pragma unroll
    for (int i = 0; i < 4; ++i)
#pragma unroll
        for (int j = 0; j < 4; ++j) acc[i][j] = fz;

    const ushort_t* Abh = (const ushort_t*)Aptr;
    const float*    Af  = (const float*)Aptr;

    const int nkt = K >> 5;
    for (int kt = 0; kt < nkt; ++kt) {
        const int kbase = kt << 5;
        if constexpr (AMODE == 0) {
#pragma unroll
            for (int j = 0; j < 2; ++j)
                gl2lds16(Af + a_off[j] + kbase, smem + lds_a[j]);
        } else {
            int node = (kbase < 256) ? pn : cn;
            gl2lds16(Abh + (size_t)node * 256 + (kbase & 255) + a_col,
                     smem + lds_a0);
        }
#pragma unroll
        for (int j = 0; j < 4; ++j)
            gl2lds16(BT + b_off[j] + kbase, (char*)Bsh + lds_b[j]);

        __syncthreads();

        s16x8 af[4], bf[4];
        if constexpr (AMODE == 0) {
            const int s = l16 & 7;
            const int c0 = (2 * quad) ^ s, c1 = c0 ^ 1;
#pragma unroll
            for (int f = 0; f < 4; ++f) {
                int row = f * 16 + l16;
                f32x4 v0 = *(const f32x4*)&Asf[row * 32 + c0 * 4];
                f32x4 v1 = *(const f32x4*)&Asf[row * 32 + c1 * 4];
                s16x8 a;
                a[0] = (short)f2bf(v0[0]); a[1] = (short)f2bf(v0[1]);
                a[2] = (short)f2bf(v0[2]); a[3] = (short)f2bf(v0[3]);
                a[4] = (short)f2bf(v1[0]); a[5] = (short)f2bf(v1[1]);
                a[6] = (short)f2bf(v1[2]); a[7] = (short)f2bf(v1[3]);
                af[f] = a;
            }
        } else {
            const int ca = quad ^ ((l16 >> 1) & 3);
#pragma unroll
            for (int f = 0; f < 4; ++f)
                af[f] = *(const s16x8*)&Ash[(f * 16 + l16) * 32 + ca * 8];
        }
        {
            const int cb = quad ^ ((l16 >> 1) & 3);
#pragma unroll
            for (int f = 0; f < 4; ++f)
                bf[f] = *(const s16x8*)&Bsh[(wc + f * 16 + l16) * 32 + cb * 8];
        }
#pragma unroll
        for (int fr = 0; fr < 4; ++fr)
#pragma unroll
            for (int fc = 0; fc < 4; ++fc)
                acc[fr][fc] = mfma16(af[fr], bf[fc], acc[fr][fc]);
        __syncthreads();
    }

    float bv[4];
#pragma unroll
    for (int fc = 0; fc < 4; ++fc) bv[fc] = bias[wc + fc * 16 + l16];

    if constexpr (EPI == 0) {
        ushort_t* out = (ushort_t*)outp;
#pragma unroll
        for (int fr = 0; fr < 4; ++fr) {
#pragma unroll
            for (int r = 0; r < 4; ++r) {
                int gr = row0 + fr * 16 + quad * 4 + r;
                if (gr < M) {
#pragma unroll
                    for (int fc = 0; fc < 4; ++fc) {
                        float v = acc[fr][fc][r] + bv[fc];
                        v = v > 0.f ? v : 0.f;
                        out[(size_t)gr * 256 + wc + fc * 16 + l16] = f2bf(v);
                    }
                }
            }
        }
    } else {
        float* out = (float*)outp;
#pragma unroll
        for (int fr = 0; fr < 4; ++fr) {
#pragma unroll
            for (int r = 0; r < 4; ++r) {
                int e = row0 + fr * 16 + quad * 4 + r;
                if (e < M) {
                    int m  = meta[e];
                    int pl = m & 15, cl = (m >> 4) & 15;
                    int op = (m >> 8) & 1, oc = (m >> 9) & 1;
#pragma unroll
                    for (int fc = 0; fc < 4; ++fc) {
                        int n = wc + fc * 16 + l16;
                        float v = acc[fr][fc][r] + bv[fc];
                        int rr = n >> 4, cc = n & 15;
                        if (op & oc)  v = (rr == pl && cc == cl) ? 0.0f : AZ;
                        else if (oc)  { if (rr != cl) v += AZ; }
                        else if (op)  { if (cc != pl) v += AZ; }
                        out[(size_t)e * 256 + n] = v;
                    }
                }
            }
        }
    }
}

// ---- fused GEMM2 + unary: 64 rows x 256 cols per block ------------------
// phase A: h2 = relu(h1 @ W2T + b2) into C-layout regs
// phase B: h2 tile -> swizzled LDS (bf16)
// phase C: h2 global write (vectorized from LDS) + unary MFMA + mask + store
__global__ __launch_bounds__(256) void gemm2_unary_kernel(
    const ushort_t* __restrict__ h1, const ushort_t* __restrict__ W2T,
    const float* __restrict__ b2, const ushort_t* __restrict__ WuTs,
    const float* __restrict__ bu, const int* __restrict__ tl,
    const int* __restrict__ obs, ushort_t* __restrict__ h2,
    float* __restrict__ out_unary, int N)
{
    __shared__ __align__(16) char smem[4096 + 16384 + 32768 + 8192];
    ushort_t* Ash = (ushort_t*)smem;               // 64 x 32
    ushort_t* Bsh = (ushort_t*)(smem + 4096);      // 256 x 32
    ushort_t* Hsh = (ushort_t*)(smem + 20480);     // 64 x 256 (chunk-swizzled)
    ushort_t* Wsh = (ushort_t*)(smem + 53248);     // 16 x 256 (pre-swizzled)

    const int tid = threadIdx.x, lane = tid & 63, wave = tid >> 6;
    const int quad = lane >> 4, l16 = lane & 15;
    const int sub4 = lane >> 2, c4 = lane & 3;
    const int n0 = blockIdx.x * 64;
    const int wc = wave * 64;

    // stage WuT (8KB, pre-swizzled in global): 2 rounds
#pragma unroll
    for (int j = 0; j < 2; ++j)
        gl2lds16(WuTs + j * 2048 + wave * 512 + lane * 8,
                 (char*)Wsh + j * 4096 + wave * 1024);

    // staging geometry
    const int gcA = c4 ^ ((sub4 >> 1) & 3);
    int gra = n0 + wave * 16 + sub4; if (gra > N - 1) gra = N - 1;
    const size_t a_goff = (size_t)gra * 256 + gcA * 8;
    const unsigned a_loff = (unsigned)wave * 1024;
    size_t b_goff[4]; unsigned b_loff[4];
#pragma unroll
    for (int j = 0; j < 4; ++j) {
        int nrow = j * 64 + wave * 16 + sub4;
        b_goff[j] = (size_t)nrow * 256 + gcA * 8;
        b_loff[j] = (unsigned)(j * 64 + wave * 16) * 64;
    }

    const f32x4 fz = {0.f, 0.f, 0.f, 0.f};
    f32x4 acc[4][4];
#pragma unroll
    for (int i = 0; i < 4; ++i)
#pragma unroll
        for (int j = 0; j < 4; ++j) acc[i][j] = fz;

    // ---- phase A: K = 256 ----
    for (int kt = 0; kt < 8; ++kt) {
        const int kbase = kt << 5;
        gl2lds16(h1 + a_goff + kbase, smem + a_loff);
#pragma unroll
        for (int j = 0; j < 4; ++j)
            gl2lds16(W2T + b_goff[j] + kbase, (char*)Bsh + b_loff[j]);
        __syncthreads();
        const int cs = quad ^ ((l16 >> 1) & 3);
        s16x8 af[4], bf[4];
#pragma unroll
        for (int f = 0; f < 4; ++f)
            af[f] = *(const s16x8*)&Ash[(f * 16 + l16) * 32 + cs * 8];
#pragma unroll
        for (int f = 0; f < 4; ++f)
            bf[f] = *(const s16x8*)&Bsh[(wc + f * 16 + l16) * 32 + cs * 8];
#pragma unroll
        for (int fr = 0; fr < 4; ++fr)
#pragma unroll
            for (int fc = 0; fc < 4; ++fc)
                acc[fr][fc] = mfma16(af[fr], bf[fc], acc[fr][fc]);
        __syncthreads();
    }

    // ---- phase B: relu+bias -> swizzled LDS ----
    float bv[4];
#pragma unroll
    for (int fc = 0; fc < 4; ++fc) bv[fc] = b2[wc + fc * 16 + l16];
#pragma unroll
    for (int fr = 0; fr < 4; ++fr) {
#pragma unroll
        for (int r = 0; r < 4; ++r) {
            int row = fr * 16 + quad * 4 + r;
#pragma unroll
            for (int fc = 0; fc < 4; ++fc) {
                int col = wc + fc * 16 + l16;
                float v = acc[fr][fc][r] + bv[fc];
                v = v > 0.f ? v : 0.f;
                Hsh[row * 256 + (((col >> 3) ^ (row & 7)) << 3) + (col & 7)] = f2bf(v);
            }
        }
    }
    __syncthreads();

    // ---- phase C1: h2 global write, vectorized+de-swizzled from LDS ----
    {
        int row = tid >> 2, cc = tid & 3;
        int gr = n0 + row;
        if (gr < N) {
#pragma unroll
            for (int j = 0; j < 8; ++j) {
                int phys = (j * 4 + cc) ^ (row & 7);
                s16x8 v = *(const s16x8*)&Hsh[row * 256 + phys * 8];
                *(s16x8*)&h2[(size_t)gr * 256 + (j * 4 + cc) * 8] = v;
            }
        }
    }

    // ---- phase C2: unary = h2_tile @ WuT, mask, store ----
    {
        const int arow = wave * 16 + l16;
        f32x4 accu = fz;
#pragma unroll
        for (int kt = 0; kt < 8; ++kt) {
            int pc = (kt * 4 + quad) ^ (l16 & 7);
            s16x8 a = *(const s16x8*)&Hsh[arow * 256 + pc * 8];
            s16x8 b = *(const s16x8*)&Wsh[l16 * 256 + pc * 8];
            accu = mfma16(a, b, accu);
        }
        float bvc = bu[l16];
#pragma unroll
        for (int r = 0; r < 4; ++r) {
            int node = n0 + wave * 16 + quad * 4 + r;
            if (node < N) {
                float v = obs[node] ? ((tl[node] == l16) ? 0.0f : AZ) : (accu[r] + bvc);
                out_unary[(size_t)node * 16 + l16] = v;
            }
        }
    }
}

// ---- launch ------------------------------------------------------------
extern "C" void kernel_launch(void* const* d_in, const int* in_sizes, int n_in,
                              void* d_out, int out_size, void* d_ws, size_t ws_size,
                              hipStream_t stream) {
    const float* features = (const float*)d_in[0];
    const int* parent_idx = (const int*)d_in[1];
    const int* child_idx  = (const int*)d_in[2];
    const int* label_obs  = (const int*)d_in[3];
    const int* true_lab   = (const int*)d_in[4];
    const float* W1 = (const float*)d_in[5];
    const float* b1 = (const float*)d_in[6];
    const float* W2 = (const float*)d_in[7];
    const float* b2 = (const float*)d_in[8];
    const float* Wu = (const float*)d_in[9];
    const float* bu = (const float*)d_in[10];
    const float* We = (const float*)d_in[11];
    const float* be = (const float*)d_in[12];
    float* out = (float*)d_out;

    const int N = 100000, E = N - 1;

    char* ws = (char*)d_ws;
    ushort_t* h1   = (ushort_t*)ws;
    ushort_t* h2   = (ushort_t*)(ws + (size_t)N * 256 * 2);
    ushort_t* W1T  = (ushort_t*)(ws + (size_t)N * 256 * 4);
    ushort_t* W2T  = W1T + 768 * 256;
    ushort_t* WeT  = W2T + 256 * 256;
    ushort_t* WuTs = WeT + 512 * 256;
    int*      meta = (int*)(WuTs + 16 * 256);

    setup_kernel<<<1943, 256, 0, stream>>>(W1, W2, We, Wu, W1T, W2T, WeT, WuTs,
                                           parent_idx, child_idx, true_lab, label_obs,
                                           meta, E);

    dim3 gn(1, (N + 63) / 64);
    gemm_kernel<0, 0><<<gn, 256, 0, stream>>>(features, W1T, b1, h1, N, 768,
                                              nullptr, nullptr, nullptr);
    gemm2_unary_kernel<<<(N + 63) / 64, 256, 0, stream>>>(h1, W2T, b2, WuTs, bu,
                                                          true_lab, label_obs, h2, out, N);
    dim3 ge(1, (E + 63) / 64);
    gemm_kernel<2, 1><<<ge, 256, 0, stream>>>(h2, WeT, be, out + (size_t)N * 16, E, 512,
                                              parent_idx, child_idx, meta);
}

// Round 2
// 608.668 us; speedup vs baseline: 1.0547x; 1.0117x over previous
//
#include <hip/hip_runtime.h>
#include <cstddef>

#define AZ -999999.0f

typedef float  f32x4  __attribute__((ext_vector_type(4)));
typedef short  s16x8  __attribute__((ext_vector_type(8)));
typedef __bf16 bf16x8 __attribute__((ext_vector_type(8)));
typedef unsigned short ushort_t;

// HW RNE f32->bf16 (compiler emits v_cvt_pk_bf16_f32 on gfx950)
__device__ __forceinline__ ushort_t f2bf(float f) {
    return __builtin_bit_cast(ushort_t, (__bf16)f);
}

__device__ __forceinline__ f32x4 mfma16(s16x8 a, s16x8 b, f32x4 c) {
    return __builtin_amdgcn_mfma_f32_16x16x32_bf16(
        __builtin_bit_cast(bf16x8, a), __builtin_bit_cast(bf16x8, b), c, 0, 0, 0);
}

// async global->LDS, 16B per lane; LDS dest = wave-uniform base + lane*16
__device__ __forceinline__ void gl2lds16(const void* g, void* l) {
    __builtin_amdgcn_global_load_lds(
        (const __attribute__((address_space(1))) unsigned int*)g,
        (__attribute__((address_space(3))) unsigned int*)l, 16, 0, 0);
}

// ---- combined setup: weight transposes+casts, Wu swizzle, edge meta ----
// blocks [0,768): W1T   [768,1024): W2T   [1024,1536): WeT
// [1536,1552): WuTs (pre-swizzled)   [1552,1943): meta
__global__ void setup_kernel(
    const float* __restrict__ W1, const float* __restrict__ W2,
    const float* __restrict__ We, const float* __restrict__ Wu,
    ushort_t* __restrict__ W1T, ushort_t* __restrict__ W2T,
    ushort_t* __restrict__ WeT, ushort_t* __restrict__ WuTs,
    const int* __restrict__ pidx, const int* __restrict__ cidx,
    const int* __restrict__ tl, const int* __restrict__ obs,
    int* __restrict__ meta, int E)
{
    int b = blockIdx.x, t = threadIdx.x;
    if (b < 768) {
        int idx = b * 256 + t; int k = idx >> 8, n = idx & 255;
        W1T[(size_t)n * 768 + k] = f2bf(W1[idx]);
    } else if (b < 1024) {
        int idx = (b - 768) * 256 + t; int k = idx >> 8, n = idx & 255;
        W2T[n * 256 + k] = f2bf(W2[idx]);
    } else if (b < 1536) {
        int idx = (b - 1024) * 256 + t; int k = idx >> 8, n = idx & 255;
        WeT[(size_t)n * 512 + k] = f2bf(We[idx]);
    } else if (b < 1552) {
        int idx = (b - 1536) * 256 + t; int k = idx >> 4, c = idx & 15;
        // WuT[c][k], stored with chunk swizzle: chunk' = (k>>3) ^ (c&7)
        WuTs[c * 256 + (((k >> 3) ^ (c & 7)) << 3) + (k & 7)] = f2bf(Wu[idx]);
    } else {
        int e = (b - 1552) * 256 + t;
        if (e < E) {
            int p = pidx[e], c = cidx[e];
            meta[e] = (tl[p] & 15) | ((tl[c] & 15) << 4)
                    | ((obs[p] & 1) << 8) | ((obs[c] & 1) << 9);
        }
    }
}

// ---- fused node pipeline: GEMM1 + GEMM2 + unary, 64 rows/block ---------
// phase 1: h1 = relu(features @ W1T + b1)  (K=768, f32 A staged to LDS)
//          -> h1 tile kept ONLY in swizzled LDS (never written to global)
// phase 2: h2 = relu(h1 @ W2T + b2)        (K=256, A read from LDS)
// phase 3: h2 tile -> LDS (reuse) -> global h2 write + unary MFMA + store
__global__ __launch_bounds__(256) void node_fused_kernel(
    const float* __restrict__ features, const ushort_t* __restrict__ W1T,
    const float* __restrict__ b1, const ushort_t* __restrict__ W2T,
    const float* __restrict__ b2, const ushort_t* __restrict__ WuTs,
    const float* __restrict__ bu, const int* __restrict__ tl,
    const int* __restrict__ obs, ushort_t* __restrict__ h2,
    float* __restrict__ out_unary, int N)
{
    __shared__ __align__(16) char smem[65536];
    float*    Asf = (float*)smem;                  // 64x32 f32 A-stage (8KB)
    ushort_t* Bsh = (ushort_t*)(smem + 8192);      // 256x32 bf16 B-stage (16KB)
    ushort_t* Hsh = (ushort_t*)(smem + 24576);     // 64x256 swizzled h1/h2 (32KB)
    ushort_t* Wsh = (ushort_t*)(smem + 57344);     // 16x256 WuT pre-swz (8KB)

    const int tid = threadIdx.x, lane = tid & 63, wave = tid >> 6;
    const int quad = lane >> 4, l16 = lane & 15;
    const int row0 = blockIdx.x * 64;
    const int wc = wave * 64;

    // stage WuT (8KB, pre-swizzled in global): 2 rounds, drains at 1st barrier
#pragma unroll
    for (int j = 0; j < 2; ++j)
        gl2lds16(WuTs + j * 2048 + wave * 512 + lane * 8,
                 (char*)Wsh + j * 4096 + wave * 1024);

    // ---- B staging geometry (shared phase1/phase2): 4 rounds of 64 rows --
    const int c4 = tid & 3, rB = tid >> 2;
    const int gcB = c4 ^ ((rB >> 1) & 3);          // 16B-chunk XOR swizzle
    unsigned lds_b[4];
#pragma unroll
    for (int j = 0; j < 4; ++j) lds_b[j] = (unsigned)(j * 64 + wave * 16) * 64;

    // ---- phase-1 A staging: 2 rounds of 32 rows of f32 -------------------
    const int c8 = tid & 7, r8 = tid >> 3;
    const int gcA = c8 ^ (r8 & 7);
    size_t a_off[2]; unsigned lds_a[2];
#pragma unroll
    for (int j = 0; j < 2; ++j) {
        int gr = row0 + j * 32 + r8; if (gr > N - 1) gr = N - 1;
        a_off[j] = (size_t)gr * 768 + gcA * 4;
        lds_a[j] = (unsigned)(j * 32 + wave * 8) * 128;
    }

    const f32x4 fz = {0.f, 0.f, 0.f, 0.f};
    f32x4 acc[4][4];
#pragma unroll
    for (int i = 0; i < 4; ++i)
#pragma unroll
        for (int j = 0; j < 4; ++j) acc[i][j] = fz;

    // ---- phase 1: K = 768 ----
    for (int kt = 0; kt < 24; ++kt) {
        const int kbase = kt << 5;
#pragma unroll
        for (int j = 0; j < 2; ++j)
            gl2lds16(features + a_off[j] + kbase, smem + lds_a[j]);
#pragma unroll
        for (int j = 0; j < 4; ++j)
            gl2lds16(W1T + (size_t)(j * 64 + rB) * 768 + gcB * 8 + kbase,
                     (char*)Bsh + lds_b[j]);
        __syncthreads();

        s16x8 af[4], bf[4];
        const int s = l16 & 7;
        const int c0 = (2 * quad) ^ s, c1 = c0 ^ 1;
#pragma unroll
        for (int f = 0; f < 4; ++f) {
            int row = f * 16 + l16;
            f32x4 v0 = *(const f32x4*)&Asf[row * 32 + c0 * 4];
            f32x4 v1 = *(const f32x4*)&Asf[row * 32 + c1 * 4];
            s16x8 a;
            a[0] = (short)f2bf(v0[0]); a[1] = (short)f2bf(v0[1]);
            a[2] = (short)f2bf(v0[2]); a[3] = (short)f2bf(v0[3]);
            a[4] = (short)f2bf(v1[0]); a[5] = (short)f2bf(v1[1]);
            a[6] = (short)f2bf(v1[2]); a[7] = (short)f2bf(v1[3]);
            af[f] = a;
        }
        const int cb = quad ^ ((l16 >> 1) & 3);
#pragma unroll
        for (int f = 0; f < 4; ++f)
            bf[f] = *(const s16x8*)&Bsh[(wc + f * 16 + l16) * 32 + cb * 8];
#pragma unroll
        for (int fr = 0; fr < 4; ++fr)
#pragma unroll
            for (int fc = 0; fc < 4; ++fc)
                acc[fr][fc] = mfma16(af[fr], bf[fc], acc[fr][fc]);
        __syncthreads();
    }

    // ---- epilogue 1: relu+b1 -> swizzled LDS (h1 tile) ----
    {
        float bv[4];
#pragma unroll
        for (int fc = 0; fc < 4; ++fc) bv[fc] = b1[wc + fc * 16 + l16];
#pragma unroll
        for (int fr = 0; fr < 4; ++fr) {
#pragma unroll
            for (int r = 0; r < 4; ++r) {
                int row = fr * 16 + quad * 4 + r;
#pragma unroll
                for (int fc = 0; fc < 4; ++fc) {
                    int col = wc + fc * 16 + l16;
                    float v = acc[fr][fc][r] + bv[fc];
                    v = v > 0.f ? v : 0.f;
                    Hsh[row * 256 + (((col >> 3) ^ (row & 7)) << 3) + (col & 7)] = f2bf(v);
                }
            }
        }
    }
#pragma unroll
    for (int i = 0; i < 4; ++i)
#pragma unroll
        for (int j = 0; j < 4; ++j) acc[i][j] = fz;

    // ---- phase 2: K = 256, A fragments straight from Hsh ----
    for (int kt = 0; kt < 8; ++kt) {
        const int kbase = kt << 5;
#pragma unroll
        for (int j = 0; j < 4; ++j)
            gl2lds16(W2T + (size_t)(j * 64 + rB) * 256 + gcB * 8 + kbase,
                     (char*)Bsh + lds_b[j]);
        __syncthreads();   // also orders epilogue-1 Hsh writes before reads

        s16x8 af[4], bf[4];
        const int pc = (kt * 4 + quad) ^ (l16 & 7);
#pragma unroll
        for (int f = 0; f < 4; ++f)
            af[f] = *(const s16x8*)&Hsh[(f * 16 + l16) * 256 + pc * 8];
        const int cb = quad ^ ((l16 >> 1) & 3);
#pragma unroll
        for (int f = 0; f < 4; ++f)
            bf[f] = *(const s16x8*)&Bsh[(wc + f * 16 + l16) * 32 + cb * 8];
#pragma unroll
        for (int fr = 0; fr < 4; ++fr)
#pragma unroll
            for (int fc = 0; fc < 4; ++fc)
                acc[fr][fc] = mfma16(af[fr], bf[fc], acc[fr][fc]);
        __syncthreads();
    }

    // ---- epilogue 2: relu+b2 -> Hsh (reuse; phase-2 reads done at barrier)
    {
        float bv[4];
#pragma unroll
        for (int fc = 0; fc < 4; ++fc) bv[fc] = b2[wc + fc * 16 + l16];
#pragma unroll
        for (int fr = 0; fr < 4; ++fr) {
#pragma unroll
            for (int r = 0; r < 4; ++r) {
                int row = fr * 16 + quad * 4 + r;
#pragma unroll
                for (int fc = 0; fc < 4; ++fc) {
                    int col = wc + fc * 16 + l16;
                    float v = acc[fr][fc][r] + bv[fc];
                    v = v > 0.f ? v : 0.f;
                    Hsh[row * 256 + (((col >> 3) ^ (row & 7)) << 3) + (col & 7)] = f2bf(v);
                }
            }
        }
    }
    __syncthreads();

    // ---- phase C1: h2 global write, vectorized+de-swizzled from LDS ----
    {
        int row = tid >> 2, cc = tid & 3;
        int gr = row0 + row;
        if (gr < N) {
#pragma unroll
            for (int j = 0; j < 8; ++j) {
                int phys = (j * 4 + cc) ^ (row & 7);
                s16x8 v = *(const s16x8*)&Hsh[row * 256 + phys * 8];
                *(s16x8*)&h2[(size_t)gr * 256 + (j * 4 + cc) * 8] = v;
            }
        }
    }

    // ---- phase C2: unary = h2_tile @ WuT, mask, store ----
    {
        const int arow = wave * 16 + l16;
        f32x4 accu = fz;
#pragma unroll
        for (int kt = 0; kt < 8; ++kt) {
            int pc = (kt * 4 + quad) ^ (l16 & 7);
            s16x8 a = *(const s16x8*)&Hsh[arow * 256 + pc * 8];
            s16x8 b = *(const s16x8*)&Wsh[l16 * 256 + pc * 8];
            accu = mfma16(a, b, accu);
        }
        float bvc = bu[l16];
#pragma unroll
        for (int r = 0; r < 4; ++r) {
            int node = row0 + wave * 16 + quad * 4 + r;
            if (node < N) {
                float v = obs[node] ? ((tl[node] == l16) ? 0.0f : AZ) : (accu[r] + bvc);
                out_unary[(size_t)node * 16 + l16] = v;
            }
        }
    }
}

// ---- edge GEMM: 64 edges x 256 cols per block, K=512 (gathered h2) -----
__global__ __launch_bounds__(256) void edge_gemm_kernel(
    const ushort_t* __restrict__ h2, const ushort_t* __restrict__ WeT,
    const float* __restrict__ bias, float* __restrict__ out,
    int M,
    const int* __restrict__ parent_idx, const int* __restrict__ child_idx,
    const int* __restrict__ meta)
{
    __shared__ __align__(16) char smem[4096 + 16384];
    ushort_t* Ash = (ushort_t*)smem;                // 64 x 32 bf16
    ushort_t* Bsh = (ushort_t*)(smem + 4096);       // 256 x 32 bf16

    const int tid  = threadIdx.x;
    const int lane = tid & 63, wave = tid >> 6;
    const int row0 = blockIdx.x * 64;
    const int wc   = wave * 64;
    const int quad = lane >> 4, l16 = lane & 15;
    const int c4   = tid & 3, rB = tid >> 2;

    const int gcB = c4 ^ ((rB >> 1) & 3);
    size_t   b_off[4]; unsigned lds_b[4];
#pragma unroll
    for (int j = 0; j < 4; ++j) {
        b_off[j] = (size_t)(j * 64 + rB) * 512 + gcB * 8;
        lds_b[j] = (unsigned)(j * 64 + wave * 16) * 64;
    }

    // A gather: 1 round of 64 rows; 4 lanes x 16B per row
    int gr = row0 + rB; if (gr > M - 1) gr = M - 1;
    const int pn = parent_idx[gr], cn = child_idx[gr];
    const unsigned a_col  = (unsigned)gcB * 8;       // same swizzle as B
    const unsigned lds_a0 = (unsigned)(wave * 16) * 64;

    const f32x4 fz = {0.f, 0.f, 0.f, 0.f};
    f32x4 acc[4][4];
#pragma unroll
    for (int i = 0; i < 4; ++i)
#pragma unroll
        for (int j = 0; j < 4; ++j) acc[i][j] = fz;

    for (int kt = 0; kt < 16; ++kt) {
        const int kbase = kt << 5;
        int node = (kbase < 256) ? pn : cn;
        gl2lds16(h2 + (size_t)node * 256 + (kbase & 255) + a_col, smem + lds_a0);
#pragma unroll
        for (int j = 0; j < 4; ++j)
            gl2lds16(WeT + b_off[j] + kbase, (char*)Bsh + lds_b[j]);

        __syncthreads();

        s16x8 af[4], bf[4];
        const int ca = quad ^ ((l16 >> 1) & 3);
#pragma unroll
        for (int f = 0; f < 4; ++f)
            af[f] = *(const s16x8*)&Ash[(f * 16 + l16) * 32 + ca * 8];
#pragma unroll
        for (int f = 0; f < 4; ++f)
            bf[f] = *(const s16x8*)&Bsh[(wc + f * 16 + l16) * 32 + ca * 8];
#pragma unroll
        for (int fr = 0; fr < 4; ++fr)
#pragma unroll
            for (int fc = 0; fc < 4; ++fc)
                acc[fr][fc] = mfma16(af[fr], bf[fc], acc[fr][fc]);
        __syncthreads();
    }

    float bv[4];
#pragma unroll
    for (int fc = 0; fc < 4; ++fc) bv[fc] = bias[wc + fc * 16 + l16];

#pragma unroll
    for (int fr = 0; fr < 4; ++fr) {
#pragma unroll
        for (int r = 0; r < 4; ++r) {
            int e = row0 + fr * 16 + quad * 4 + r;
            if (e < M) {
                int m  = meta[e];
                int pl = m & 15, cl = (m >> 4) & 15;
                int op = (m >> 8) & 1, oc = (m >> 9) & 1;
#pragma unroll
                for (int fc = 0; fc < 4; ++fc) {
                    int n = wc + fc * 16 + l16;
                    float v = acc[fr][fc][r] + bv[fc];
                    int rr = n >> 4, cc = n & 15;
                    if (op & oc)  v = (rr == pl && cc == cl) ? 0.0f : AZ;
                    else if (oc)  { if (rr != cl) v += AZ; }
                    else if (op)  { if (cc != pl) v += AZ; }
                    out[(size_t)e * 256 + n] = v;
                }
            }
        }
    }
}

// ---- launch ------------------------------------------------------------
extern "C" void kernel_launch(void* const* d_in, const int* in_sizes, int n_in,
                              void* d_out, int out_size, void* d_ws, size_t ws_size,
                              hipStream_t stream) {
    const float* features = (const float*)d_in[0];
    const int* parent_idx = (const int*)d_in[1];
    const int* child_idx  = (const int*)d_in[2];
    const int* label_obs  = (const int*)d_in[3];
    const int* true_lab   = (const int*)d_in[4];
    const float* W1 = (const float*)d_in[5];
    const float* b1 = (const float*)d_in[6];
    const float* W2 = (const float*)d_in[7];
    const float* b2 = (const float*)d_in[8];
    const float* Wu = (const float*)d_in[9];
    const float* bu = (const float*)d_in[10];
    const float* We = (const float*)d_in[11];
    const float* be = (const float*)d_in[12];
    float* out = (float*)d_out;

    const int N = 100000, E = N - 1;

    char* ws = (char*)d_ws;
    ushort_t* h2   = (ushort_t*)ws;                       // N*256 bf16
    ushort_t* W1T  = (ushort_t*)(ws + (size_t)N * 256 * 2);
    ushort_t* W2T  = W1T + 768 * 256;
    ushort_t* WeT  = W2T + 256 * 256;
    ushort_t* WuTs = WeT + 512 * 256;
    int*      meta = (int*)(WuTs + 16 * 256);

    setup_kernel<<<1943, 256, 0, stream>>>(W1, W2, We, Wu, W1T, W2T, WeT, WuTs,
                                           parent_idx, child_idx, true_lab, label_obs,
                                           meta, E);

    node_fused_kernel<<<(N + 63) / 64, 256, 0, stream>>>(
        features, W1T, b1, W2T, b2, WuTs, bu, true_lab, label_obs, h2, out, N);

    edge_gemm_kernel<<<(E + 63) / 64, 256, 0, stream>>>(
        h2, WeT, be, out + (size_t)N * 16, E, parent_idx, child_idx, meta);
}

// Round 4
// 574.447 us; speedup vs baseline: 1.1175x; 1.0596x over previous
//
#include <hip/hip_runtime.h>
#include <cstddef>

#define AZ -999999.0f

typedef float  f32x4  __attribute__((ext_vector_type(4)));
typedef short  s16x8  __attribute__((ext_vector_type(8)));
typedef __bf16 bf16x8 __attribute__((ext_vector_type(8)));
typedef unsigned short ushort_t;

// HW RNE f32->bf16 (compiler emits v_cvt_pk_bf16_f32 on gfx950)
__device__ __forceinline__ ushort_t f2bf(float f) {
    return __builtin_bit_cast(ushort_t, (__bf16)f);
}

__device__ __forceinline__ f32x4 mfma16(s16x8 a, s16x8 b, f32x4 c) {
    return __builtin_amdgcn_mfma_f32_16x16x32_bf16(
        __builtin_bit_cast(bf16x8, a), __builtin_bit_cast(bf16x8, b), c, 0, 0, 0);
}

// async global->LDS, 16B per lane; LDS dest = wave-uniform base + lane*16
__device__ __forceinline__ void gl2lds16(const void* g, void* l) {
    __builtin_amdgcn_global_load_lds(
        (const __attribute__((address_space(1))) unsigned int*)g,
        (__attribute__((address_space(3))) unsigned int*)l, 16, 0, 0);
}

// compiler memory fence so LDS/global ops cannot be hoisted/sunk across
// a raw s_barrier (rule #18 analog).
#define FENCE() asm volatile("" ::: "memory")

// ---- combined setup: weight transposes+casts, Wu swizzle, edge meta ----
__global__ void setup_kernel(
    const float* __restrict__ W1, const float* __restrict__ W2,
    const float* __restrict__ We, const float* __restrict__ Wu,
    ushort_t* __restrict__ W1T, ushort_t* __restrict__ W2T,
    ushort_t* __restrict__ WeT, ushort_t* __restrict__ WuTs,
    const int* __restrict__ pidx, const int* __restrict__ cidx,
    const int* __restrict__ tl, const int* __restrict__ obs,
    int* __restrict__ meta, int E)
{
    int b = blockIdx.x, t = threadIdx.x;
    if (b < 768) {
        int idx = b * 256 + t; int k = idx >> 8, n = idx & 255;
        W1T[(size_t)n * 768 + k] = f2bf(W1[idx]);
    } else if (b < 1024) {
        int idx = (b - 768) * 256 + t; int k = idx >> 8, n = idx & 255;
        W2T[n * 256 + k] = f2bf(W2[idx]);
    } else if (b < 1536) {
        int idx = (b - 1024) * 256 + t; int k = idx >> 8, n = idx & 255;
        WeT[(size_t)n * 512 + k] = f2bf(We[idx]);
    } else if (b < 1552) {
        int idx = (b - 1536) * 256 + t; int k = idx >> 4, c = idx & 15;
        // WuT[c][k], stored with chunk swizzle: chunk' = (k>>3) ^ (c&7)
        WuTs[c * 256 + (((k >> 3) ^ (c & 7)) << 3) + (k & 7)] = f2bf(Wu[idx]);
    } else {
        int e = (b - 1552) * 256 + t;
        if (e < E) {
            int p = pidx[e], c = cidx[e];
            meta[e] = (tl[p] & 15) | ((tl[c] & 15) << 4)
                    | ((obs[p] & 1) << 8) | ((obs[c] & 1) << 9);
        }
    }
}

// ---- fused node pipeline: GEMM1 + GEMM2 + unary, 64 rows/block ---------
// Double-buffered, counted-vmcnt pipeline (T3+T4). LDS re-use by phase:
//   phase 1 : A f32 dbuf [0,16K)   B dbuf [16K,32K)+[32K,48K)
//   phase 2 : B dbuf [16K,32K)+[0,16K)    Hsh [32K,64K)
__global__ __launch_bounds__(256) void node_fused_kernel(
    const float* __restrict__ features, const ushort_t* __restrict__ W1T,
    const float* __restrict__ b1, const ushort_t* __restrict__ W2T,
    const float* __restrict__ b2, const ushort_t* __restrict__ WuTs,
    const float* __restrict__ bu, const int* __restrict__ tl,
    const int* __restrict__ obs, ushort_t* __restrict__ h2,
    float* __restrict__ out_unary, int N)
{
    __shared__ __align__(16) char smem[65536];
    ushort_t* Hsh = (ushort_t*)(smem + 32768);     // 64 x 256 swizzled (32KB)

    const int tid = threadIdx.x, lane = tid & 63, wave = tid >> 6;
    const int quad = lane >> 4, l16 = lane & 15;
    const int row0 = blockIdx.x * 64;
    const int wc = wave * 64;

    // B staging geometry: 4 rounds of 64 rows; row = j*64 + (tid>>2)
    const int c4 = tid & 3, rB = tid >> 2;
    const int gcB = c4 ^ ((rB >> 1) & 3);          // 16B-chunk XOR swizzle
    unsigned lds_b[4]; size_t b1_off[4];
#pragma unroll
    for (int j = 0; j < 4; ++j) {
        lds_b[j]  = (unsigned)(j * 64 + wave * 16) * 64;
        b1_off[j] = (size_t)(j * 64 + rB) * 768 + gcB * 8;
    }

    // phase-1 A staging: 2 rounds of 32 rows of f32
    const int c8 = tid & 7, r8 = tid >> 3;
    const int gcA = c8 ^ (r8 & 7);
    size_t a_off[2]; unsigned lds_a[2];
#pragma unroll
    for (int j = 0; j < 2; ++j) {
        int gr = row0 + j * 32 + r8; if (gr > N - 1) gr = N - 1;
        a_off[j] = (size_t)gr * 768 + gcA * 4;
        lds_a[j] = (unsigned)(j * 32 + wave * 8) * 128;
    }

    const f32x4 fz = {0.f, 0.f, 0.f, 0.f};
    f32x4 acc[4][4];
#pragma unroll
    for (int i = 0; i < 4; ++i)
#pragma unroll
        for (int j = 0; j < 4; ++j) acc[i][j] = fz;

    auto stageA = [&](int kt, int b) {
        const int kbase = kt << 5;
        char* Ab = smem + b * 8192;
#pragma unroll
        for (int j = 0; j < 2; ++j)
            gl2lds16(features + a_off[j] + kbase, Ab + lds_a[j]);
    };
    auto stageB1 = [&](int kt, int b) {
        const int kbase = kt << 5;
        char* Bb = smem + 16384 + b * 16384;
#pragma unroll
        for (int j = 0; j < 4; ++j)
            gl2lds16(W1T + b1_off[j] + kbase, Bb + lds_b[j]);
    };
    auto stageB2 = [&](int kt, int b) {            // phase-2 bufs: 0->16K, 1->0
        const int kbase = kt << 5;
        char* Bb = smem + (b ? 0 : 16384);
#pragma unroll
        for (int j = 0; j < 4; ++j)
            gl2lds16(W2T + (size_t)(j * 64 + rB) * 256 + gcB * 8 + kbase,
                     Bb + lds_b[j]);
    };

    // ---- phase 1: K = 768, full dbuf pipeline ----
    stageA(0, 0); stageB1(0, 0);
    int cur = 0;
    for (int kt = 0; kt < 24; ++kt) {
        if (kt < 23) {
            stageA(kt + 1, cur ^ 1); stageB1(kt + 1, cur ^ 1);
            asm volatile("s_waitcnt vmcnt(6)" ::: "memory");
        } else {
            stageB2(0, 0);                         // prefetch phase-2 tile 0
            asm volatile("s_waitcnt vmcnt(4)" ::: "memory");
        }
        __builtin_amdgcn_s_barrier();
        FENCE();

        const float*    Asf = (const float*)(smem + cur * 8192);
        const ushort_t* Bsh = (const ushort_t*)(smem + 16384 + cur * 16384);
        s16x8 af[4], bf[4];
        const int s = l16 & 7;
        const int c0 = (2 * quad) ^ s, c1 = c0 ^ 1;
#pragma unroll
        for (int f = 0; f < 4; ++f) {
            int row = f * 16 + l16;
            f32x4 v0 = *(const f32x4*)&Asf[row * 32 + c0 * 4];
            f32x4 v1 = *(const f32x4*)&Asf[row * 32 + c1 * 4];
            s16x8 a;
            a[0] = (short)f2bf(v0[0]); a[1] = (short)f2bf(v0[1]);
            a[2] = (short)f2bf(v0[2]); a[3] = (short)f2bf(v0[3]);
            a[4] = (short)f2bf(v1[0]); a[5] = (short)f2bf(v1[1]);
            a[6] = (short)f2bf(v1[2]); a[7] = (short)f2bf(v1[3]);
            af[f] = a;
        }
        const int cb = quad ^ ((l16 >> 1) & 3);
#pragma unroll
        for (int f = 0; f < 4; ++f)
            bf[f] = *(const s16x8*)&Bsh[(wc + f * 16 + l16) * 32 + cb * 8];
#pragma unroll
        for (int fr = 0; fr < 4; ++fr)
#pragma unroll
            for (int fc = 0; fc < 4; ++fc)
                acc[fr][fc] = mfma16(af[fr], bf[fc], acc[fr][fc]);

        FENCE();
        __builtin_amdgcn_s_barrier();
        cur ^= 1;
    }

    // ---- epilogue 1: relu+b1 -> swizzled Hsh (overwrites dead B-buf1) ----
    {
        float bv[4];
#pragma unroll
        for (int fc = 0; fc < 4; ++fc) bv[fc] = b1[wc + fc * 16 + l16];
#pragma unroll
        for (int fr = 0; fr < 4; ++fr) {
#pragma unroll
            for (int r = 0; r < 4; ++r) {
                int row = fr * 16 + quad * 4 + r;
#pragma unroll
                for (int fc = 0; fc < 4; ++fc) {
                    int col = wc + fc * 16 + l16;
                    float v = acc[fr][fc][r] + bv[fc];
                    v = v > 0.f ? v : 0.f;
                    Hsh[row * 256 + (((col >> 3) ^ (row & 7)) << 3) + (col & 7)] = f2bf(v);
                }
            }
        }
    }
#pragma unroll
    for (int i = 0; i < 4; ++i)
#pragma unroll
        for (int j = 0; j < 4; ++j) acc[i][j] = fz;

    asm volatile("s_waitcnt lgkmcnt(0)" ::: "memory");  // Hsh writes visible
    __builtin_amdgcn_s_barrier();
    FENCE();

    // ---- phase 2: K = 256, B dbuf pipeline, A straight from Hsh ----
    int cur2 = 0;
    for (int kt = 0; kt < 8; ++kt) {
        if (kt < 7) {
            stageB2(kt + 1, cur2 ^ 1);
            asm volatile("s_waitcnt vmcnt(4)" ::: "memory");
        } else {
            asm volatile("s_waitcnt vmcnt(0)" ::: "memory");
        }
        __builtin_amdgcn_s_barrier();
        FENCE();

        const ushort_t* Bsh = (const ushort_t*)(smem + (cur2 ? 0 : 16384));
        s16x8 af[4], bf[4];
        const int pc = (kt * 4 + quad) ^ (l16 & 7);
#pragma unroll
        for (int f = 0; f < 4; ++f)
            af[f] = *(const s16x8*)&Hsh[(f * 16 + l16) * 256 + pc * 8];
        const int cb = quad ^ ((l16 >> 1) & 3);
#pragma unroll
        for (int f = 0; f < 4; ++f)
            bf[f] = *(const s16x8*)&Bsh[(wc + f * 16 + l16) * 32 + cb * 8];
#pragma unroll
        for (int fr = 0; fr < 4; ++fr)
#pragma unroll
            for (int fc = 0; fc < 4; ++fc)
                acc[fr][fc] = mfma16(af[fr], bf[fc], acc[fr][fc]);

        FENCE();
        __builtin_amdgcn_s_barrier();
        cur2 ^= 1;
    }

    // ---- epilogue 2: relu+b2 -> Hsh (all phase-2 reads done at barrier) ----
    {
        float bv[4];
#pragma unroll
        for (int fc = 0; fc < 4; ++fc) bv[fc] = b2[wc + fc * 16 + l16];
#pragma unroll
        for (int fr = 0; fr < 4; ++fr) {
#pragma unroll
            for (int r = 0; r < 4; ++r) {
                int row = fr * 16 + quad * 4 + r;
#pragma unroll
                for (int fc = 0; fc < 4; ++fc) {
                    int col = wc + fc * 16 + l16;
                    float v = acc[fr][fc][r] + bv[fc];
                    v = v > 0.f ? v : 0.f;
                    Hsh[row * 256 + (((col >> 3) ^ (row & 7)) << 3) + (col & 7)] = f2bf(v);
                }
            }
        }
    }
    asm volatile("s_waitcnt lgkmcnt(0)" ::: "memory");
    __builtin_amdgcn_s_barrier();
    FENCE();

    // ---- phase C1: h2 global write, vectorized+de-swizzled from LDS ----
    {
        int row = tid >> 2, cc = tid & 3;
        int gr = row0 + row;
        if (gr < N) {
#pragma unroll
            for (int j = 0; j < 8; ++j) {
                int phys = (j * 4 + cc) ^ (row & 7);
                s16x8 v = *(const s16x8*)&Hsh[row * 256 + phys * 8];
                *(s16x8*)&h2[(size_t)gr * 256 + (j * 4 + cc) * 8] = v;
            }
        }
    }

    // ---- phase C2: unary = h2_tile @ WuT (WuTs read from global/L2) ----
    {
        const int arow = wave * 16 + l16;
        f32x4 accu = fz;
#pragma unroll
        for (int kt = 0; kt < 8; ++kt) {
            int pc = (kt * 4 + quad) ^ (l16 & 7);
            s16x8 a = *(const s16x8*)&Hsh[arow * 256 + pc * 8];
            s16x8 b = *(const s16x8*)&WuTs[l16 * 256 + pc * 8];
            accu = mfma16(a, b, accu);
        }
        float bvc = bu[l16];
#pragma unroll
        for (int r = 0; r < 4; ++r) {
            int node = row0 + wave * 16 + quad * 4 + r;
            if (node < N) {
                float v = obs[node] ? ((tl[node] == l16) ? 0.0f : AZ) : (accu[r] + bvc);
                out_unary[(size_t)node * 16 + l16] = v;
            }
        }
    }
}

// ---- edge GEMM: 64 edges x 256 cols, K=512, full dbuf pipeline ---------
__global__ __launch_bounds__(256) void edge_gemm_kernel(
    const ushort_t* __restrict__ h2, const ushort_t* __restrict__ WeT,
    const float* __restrict__ bias, float* __restrict__ out,
    int M,
    const int* __restrict__ parent_idx, const int* __restrict__ child_idx,
    const int* __restrict__ meta)
{
    __shared__ __align__(16) char smem[40960];
    // A dbuf [0,4K)+[4K,8K); B dbuf [8K,24K)+[24K,40K)

    const int tid  = threadIdx.x;
    const int lane = tid & 63, wave = tid >> 6;
    const int row0 = blockIdx.x * 64;
    const int wc   = wave * 64;
    const int quad = lane >> 4, l16 = lane & 15;
    const int c4   = tid & 3, rB = tid >> 2;

    const int gcB = c4 ^ ((rB >> 1) & 3);
    size_t   b_off[4]; unsigned lds_b[4];
#pragma unroll
    for (int j = 0; j < 4; ++j) {
        b_off[j] = (size_t)(j * 64 + rB) * 512 + gcB * 8;
        lds_b[j] = (unsigned)(j * 64 + wave * 16) * 64;
    }

    // A gather: 1 round of 64 rows; 4 lanes x 16B per row
    int gr = row0 + rB; if (gr > M - 1) gr = M - 1;
    const int pn = parent_idx[gr], cn = child_idx[gr];
    const unsigned a_col  = (unsigned)gcB * 8;
    const unsigned lds_a0 = (unsigned)(wave * 16) * 64;

    auto stage = [&](int kt, int b) {
        const int kbase = kt << 5;
        int node = (kbase < 256) ? pn : cn;
        gl2lds16(h2 + (size_t)node * 256 + (kbase & 255) + a_col,
                 smem + b * 4096 + lds_a0);
#pragma unroll
        for (int j = 0; j < 4; ++j)
            gl2lds16(WeT + b_off[j] + kbase,
                     smem + 8192 + b * 16384 + lds_b[j]);
    };

    const f32x4 fz = {0.f, 0.f, 0.f, 0.f};
    f32x4 acc[4][4];
#pragma unroll
    for (int i = 0; i < 4; ++i)
#pragma unroll
        for (int j = 0; j < 4; ++j) acc[i][j] = fz;

    stage(0, 0);
    int cur = 0;
    for (int kt = 0; kt < 16; ++kt) {
        if (kt < 15) {
            stage(kt + 1, cur ^ 1);
            asm volatile("s_waitcnt vmcnt(5)" ::: "memory");
        } else {
            asm volatile("s_waitcnt vmcnt(0)" ::: "memory");
        }
        __builtin_amdgcn_s_barrier();
        FENCE();

        const ushort_t* Ash = (const ushort_t*)(smem + cur * 4096);
        const ushort_t* Bsh = (const ushort_t*)(smem + 8192 + cur * 16384);
        s16x8 af[4], bf[4];
        const int ca = quad ^ ((l16 >> 1) & 3);
#pragma unroll
        for (int f = 0; f < 4; ++f)
            af[f] = *(const s16x8*)&Ash[(f * 16 + l16) * 32 + ca * 8];
#pragma unroll
        for (int f = 0; f < 4; ++f)
            bf[f] = *(const s16x8*)&Bsh[(wc + f * 16 + l16) * 32 + ca * 8];
#pragma unroll
        for (int fr = 0; fr < 4; ++fr)
#pragma unroll
            for (int fc = 0; fc < 4; ++fc)
                acc[fr][fc] = mfma16(af[fr], bf[fc], acc[fr][fc]);

        FENCE();
        __builtin_amdgcn_s_barrier();
        cur ^= 1;
    }

    float bv[4];
#pragma unroll
    for (int fc = 0; fc < 4; ++fc) bv[fc] = bias[wc + fc * 16 + l16];

#pragma unroll
    for (int fr = 0; fr < 4; ++fr) {
#pragma unroll
        for (int r = 0; r < 4; ++r) {
            int e = row0 + fr * 16 + quad * 4 + r;
            if (e < M) {
                int m  = meta[e];
                int pl = m & 15, cl = (m >> 4) & 15;
                int op = (m >> 8) & 1, oc = (m >> 9) & 1;
#pragma unroll
                for (int fc = 0; fc < 4; ++fc) {
                    int n = wc + fc * 16 + l16;
                    float v = acc[fr][fc][r] + bv[fc];
                    int rr = n >> 4, cc = n & 15;
                    if (op & oc)  v = (rr == pl && cc == cl) ? 0.0f : AZ;
                    else if (oc)  { if (rr != cl) v += AZ; }
                    else if (op)  { if (cc != pl) v += AZ; }
                    out[(size_t)e * 256 + n] = v;
                }
            }
        }
    }
}

// ---- launch ------------------------------------------------------------
extern "C" void kernel_launch(void* const* d_in, const int* in_sizes, int n_in,
                              void* d_out, int out_size, void* d_ws, size_t ws_size,
                              hipStream_t stream) {
    const float* features = (const float*)d_in[0];
    const int* parent_idx = (const int*)d_in[1];
    const int* child_idx  = (const int*)d_in[2];
    const int* label_obs  = (const int*)d_in[3];
    const int* true_lab   = (const int*)d_in[4];
    const float* W1 = (const float*)d_in[5];
    const float* b1 = (const float*)d_in[6];
    const float* W2 = (const float*)d_in[7];
    const float* b2 = (const float*)d_in[8];
    const float* Wu = (const float*)d_in[9];
    const float* bu = (const float*)d_in[10];
    const float* We = (const float*)d_in[11];
    const float* be = (const float*)d_in[12];
    float* out = (float*)d_out;

    const int N = 100000, E = N - 1;

    char* ws = (char*)d_ws;
    ushort_t* h2   = (ushort_t*)ws;                       // N*256 bf16
    ushort_t* W1T  = (ushort_t*)(ws + (size_t)N * 256 * 2);
    ushort_t* W2T  = W1T + 768 * 256;
    ushort_t* WeT  = W2T + 256 * 256;
    ushort_t* WuTs = WeT + 512 * 256;
    int*      meta = (int*)(WuTs + 16 * 256);

    setup_kernel<<<1943, 256, 0, stream>>>(W1, W2, We, Wu, W1T, W2T, WeT, WuTs,
                                           parent_idx, child_idx, true_lab, label_obs,
                                           meta, E);

    node_fused_kernel<<<(N + 63) / 64, 256, 0, stream>>>(
        features, W1T, b1, W2T, b2, WuTs, bu, true_lab, label_obs, h2, out, N);

    edge_gemm_kernel<<<(E + 63) / 64, 256, 0, stream>>>(
        h2, WeT, be, out + (size_t)N * 16, E, parent_idx, child_idx, meta);
}